// Round 3
// baseline (1144.969 us; speedup 1.0000x reference)
//
#include <hip/hip_runtime.h>
#include <hip/hip_bf16.h>
#include <math.h>

#define D 1024
#define SEQ 2048
#define MTOT 4096
#define NVOC 32000

using bf16 = __hip_bfloat16;
using bf16x8 = __attribute__((ext_vector_type(8))) __bf16;
using f32x4  = __attribute__((ext_vector_type(4))) float;
using i32x4  = __attribute__((ext_vector_type(4))) int;

#define GLD16(g, l)                                                            \
  __builtin_amdgcn_global_load_lds(                                            \
      (const __attribute__((address_space(1))) unsigned int*)(g),              \
      (__attribute__((address_space(3))) unsigned int*)(l), 16, 0, 0)

__device__ __forceinline__ void cvt8_store(const float* __restrict__ src,
                                           bf16* __restrict__ dst) {
  float4 a = *(const float4*)src;
  float4 b = *(const float4*)(src + 4);
  union { bf16 h[8]; i32x4 v; } u;
  u.h[0] = __float2bfloat16(a.x); u.h[1] = __float2bfloat16(a.y);
  u.h[2] = __float2bfloat16(a.z); u.h[3] = __float2bfloat16(a.w);
  u.h[4] = __float2bfloat16(b.x); u.h[5] = __float2bfloat16(b.y);
  u.h[6] = __float2bfloat16(b.z); u.h[7] = __float2bfloat16(b.w);
  *(i32x4*)dst = u.v;
}

// gather token embeddings -> bf16 [4096,1024]
__global__ void gather_embed_k(const int* __restrict__ x,
                               const float* __restrict__ emb,
                               bf16* __restrict__ e) {
  int gid = blockIdx.x * 256 + threadIdx.x;   // MTOT*D/8 threads
  int row = gid >> 7;
  int c8  = (gid & 127) << 3;
  int tok = x[row];
  cvt8_store(emb + (size_t)tok * D + c8, e + (size_t)gid * 8);
}

// convert wq,wk,wv -> concatenated bf16 [3072,1024]; concat biases f32 [3072]
__global__ void conv_wqkv_k(const float* __restrict__ wq, const float* __restrict__ wk,
                            const float* __restrict__ wv, const float* __restrict__ bq,
                            const float* __restrict__ bk, const float* __restrict__ bv,
                            bf16* __restrict__ w, float* __restrict__ b) {
  int gid = blockIdx.x * 256 + threadIdx.x;   // 3*D*D/8 threads
  int n = gid >> 7;
  int c8 = (gid & 127) << 3;
  const float* src = (n < 1024) ? (wq + (size_t)n * D)
                   : (n < 2048) ? (wk + (size_t)(n - 1024) * D)
                                : (wv + (size_t)(n - 2048) * D);
  cvt8_store(src + c8, w + (size_t)gid * 8);
  if (gid < 3072)
    b[gid] = (gid < 1024) ? bq[gid] : (gid < 2048) ? bk[gid - 1024] : bv[gid - 2048];
}

// convert wo -> bf16 [32000,1024]
__global__ void conv_wo_k(const float* __restrict__ wo, bf16* __restrict__ w) {
  int gid = blockIdx.x * 256 + threadIdx.x;   // NVOC*D/8 threads
  cvt8_store(wo + (size_t)gid * 8, w + (size_t)gid * 8);
}

// V [4096,1024] -> VT [2][1024][2048]
__global__ void transp_v_k(const bf16* __restrict__ V, bf16* __restrict__ VT) {
  __shared__ bf16 t[32][33];
  int tid = threadIdx.x;
  int r = tid >> 3, c4 = (tid & 7) << 2;
  int srow = blockIdx.y << 5;       // global seq-row base
  int e0   = blockIdx.x << 5;       // feature base
  const bf16* src = V + (size_t)(srow + r) * D + e0 + c4;
  ushort4 u = *(const ushort4*)src;
  t[r][c4 + 0] = ((const bf16*)&u)[0];
  t[r][c4 + 1] = ((const bf16*)&u)[1];
  t[r][c4 + 2] = ((const bf16*)&u)[2];
  t[r][c4 + 3] = ((const bf16*)&u)[3];
  __syncthreads();
  int e = tid >> 3, s4 = (tid & 7) << 2;
  int batch = srow >> 11;
  int sb = (srow & 2047) + s4;
  ushort4 o;
  ((bf16*)&o)[0] = t[s4 + 0][e];
  ((bf16*)&o)[1] = t[s4 + 1][e];
  ((bf16*)&o)[2] = t[s4 + 2][e];
  ((bf16*)&o)[3] = t[s4 + 3][e];
  *(ushort4*)(VT + (size_t)batch * D * SEQ + (size_t)(e0 + e) * SEQ + sb) = o;
}

// 128x128-tile B^T GEMM (A [M,K] row-major, B [N,K] row-major), 4 waves, BK=32.
// EPI: 0 = QKV (bias + elu+1 on Q/K, bf16 out to Q|K|V)
//      1 = logits (bias, f32 out)
//      2 = causal P (mask col<=row, bf16 out; upper tiles zero-filled)
//      3 = plain bf16 out (O = P*V)
template <int EPI>
__global__ __launch_bounds__(256, 2) void gemm_bt(
    const bf16* __restrict__ A, int lda, long long sA,
    const bf16* __restrict__ B, int ldb, long long sB,
    bf16* __restrict__ obf, long long sO,
    float* __restrict__ of32,
    const float* __restrict__ bias, int K) {
  __shared__ bf16 lA[128 * 32];
  __shared__ bf16 lB[128 * 32];
  const int tid = threadIdx.x;
  const int w = tid >> 6, l = tid & 63;
  const int m0 = blockIdx.y << 7, n0 = blockIdx.x << 7;
  const int z = blockIdx.z;
  A += (size_t)z * sA;
  B += (size_t)z * sB;
  if constexpr (EPI == 2 || EPI == 3) obf += (size_t)z * sO;
  if constexpr (EPI == 2) {
    if (blockIdx.x > blockIdx.y) {            // tile fully above diagonal
      i32x4 zz = {0, 0, 0, 0};
      #pragma unroll
      for (int it = 0; it < 8; ++it) {
        int ch = it * 256 + tid;
        *(i32x4*)(obf + (size_t)(m0 + (ch >> 4)) * SEQ + n0 + ((ch & 15) << 3)) = zz;
      }
      return;
    }
  }

  f32x4 acc[4][4] = {};
  const int wr = w >> 1, wc = w & 1;
  const int lrow = l & 15, lk = (l >> 4) << 3;

  for (int kt = 0; kt < K; kt += 32) {
    __syncthreads();
    #pragma unroll
    for (int r = 0; r < 2; ++r) {
      int g = r * 256 + tid;
      int row = g >> 2, c4 = (g & 3) << 3;
      int lbase = (r * 256 + w * 64) * 16;    // wave-uniform LDS byte base
      GLD16(A + (size_t)(m0 + row) * lda + kt + c4, (char*)lA + lbase);
      GLD16(B + (size_t)(n0 + row) * ldb + kt + c4, (char*)lB + lbase);
    }
    __syncthreads();
    bf16x8 av[4], bv[4];
    #pragma unroll
    for (int f = 0; f < 4; ++f) {
      av[f] = *reinterpret_cast<const bf16x8*>(lA + ((wr * 64 + f * 16 + lrow) * 32 + lk));
      bv[f] = *reinterpret_cast<const bf16x8*>(lB + ((wc * 64 + f * 16 + lrow) * 32 + lk));
    }
    #pragma unroll
    for (int mf = 0; mf < 4; ++mf)
      #pragma unroll
      for (int nf = 0; nf < 4; ++nf)
        acc[mf][nf] = __builtin_amdgcn_mfma_f32_16x16x32_bf16(av[mf], bv[nf], acc[mf][nf], 0, 0, 0);
  }

  const int rbase = m0 + wr * 64 + ((l >> 4) << 2);
  const int cbase = n0 + wc * 64 + (l & 15);
  #pragma unroll
  for (int mf = 0; mf < 4; ++mf) {
    #pragma unroll
    for (int nf = 0; nf < 4; ++nf) {
      #pragma unroll
      for (int i = 0; i < 4; ++i) {
        int rr = rbase + mf * 16 + i;
        int cc = cbase + nf * 16;
        float v = acc[mf][nf][i];
        if constexpr (EPI == 0) {
          v += bias[cc];
          int widx = cc >> 10;
          if (widx < 2) v = (v > 0.f) ? (v + 1.f) : expf(v);   // elu(x)+1
          obf[(size_t)widx * ((size_t)MTOT * D) + (size_t)rr * D + (cc & 1023)] =
              __float2bfloat16(v);
        } else if constexpr (EPI == 2) {
          obf[(size_t)rr * SEQ + cc] = __float2bfloat16(cc <= rr ? v : 0.f);
        } else if constexpr (EPI == 3) {
          obf[(size_t)rr * D + cc] = __float2bfloat16(v);
        } else {
          of32[(size_t)rr * NVOC + cc] = v + bias[cc];
        }
      }
    }
  }
}

extern "C" void kernel_launch(void* const* d_in, const int* in_sizes, int n_in,
                              void* d_out, int out_size, void* d_ws, size_t ws_size,
                              hipStream_t stream) {
  const int*   x   = (const int*)d_in[0];
  const float* emb = (const float*)d_in[1];
  const float* wq  = (const float*)d_in[2];
  const float* bq  = (const float*)d_in[3];
  const float* wk  = (const float*)d_in[4];
  const float* bk  = (const float*)d_in[5];
  const float* wv  = (const float*)d_in[6];
  const float* bv  = (const float*)d_in[7];
  const float* wo  = (const float*)d_in[8];
  const float* bo  = (const float*)d_in[9];
  float* out = (float*)d_out;

  char* p = (char*)d_ws;
  auto alloc = [&](size_t bytes) {
    char* r = p; p += (bytes + 255) & ~(size_t)255; return r;
  };
  bf16*  eb   = (bf16*)alloc((size_t)MTOT * D * 2);
  bf16*  wqkv = (bf16*)alloc((size_t)3 * D * D * 2);
  float* bqkv = (float*)alloc((size_t)3 * D * 4);
  bf16*  wob  = (bf16*)alloc((size_t)NVOC * D * 2);
  bf16*  Qb   = (bf16*)alloc((size_t)3 * MTOT * D * 2);   // Q|K|V contiguous
  bf16*  VT   = (bf16*)alloc((size_t)2 * D * SEQ * 2);
  bf16*  P    = (bf16*)alloc((size_t)2 * SEQ * SEQ * 2);
  bf16*  O    = (bf16*)alloc((size_t)MTOT * D * 2);
  bf16*  Kb = Qb + (size_t)MTOT * D;
  bf16*  Vb = Kb + (size_t)MTOT * D;

  gather_embed_k<<<MTOT * D / 8 / 256, 256, 0, stream>>>(x, emb, eb);
  conv_wqkv_k<<<3 * D * D / 8 / 256, 256, 0, stream>>>(wq, wk, wv, bq, bk, bv, wqkv, bqkv);
  conv_wo_k<<<NVOC * D / 8 / 256, 256, 0, stream>>>(wo, wob);

  // QKV projection: [4096,1024] x [3072,1024]^T
  gemm_bt<0><<<dim3(24, 32, 1), 256, 0, stream>>>(
      eb, D, 0LL, wqkv, D, 0LL, Qb, 0LL, nullptr, bqkv, D);

  // V -> VT for the PV GEMM
  transp_v_k<<<dim3(32, 128, 1), 256, 0, stream>>>(Vb, VT);

  // P = tril(Q K^T) per batch
  gemm_bt<2><<<dim3(16, 16, 2), 256, 0, stream>>>(
      Qb, D, (long long)SEQ * D, Kb, D, (long long)SEQ * D,
      P, (long long)SEQ * SEQ, nullptr, nullptr, D);

  // O = P V per batch
  gemm_bt<3><<<dim3(8, 16, 2), 256, 0, stream>>>(
      P, SEQ, (long long)SEQ * SEQ, VT, SEQ, (long long)D * SEQ,
      O, (long long)SEQ * D, nullptr, nullptr, SEQ);

  // logits = O wo^T + bo  -> f32 out [4096,32000]
  gemm_bt<1><<<dim3(250, 32, 1), 256, 0, stream>>>(
      O, D, 0LL, wob, D, 0LL, nullptr, 0LL, out, bo, D);
}